// Round 18
// baseline (197.216 us; speedup 1.0000x reference)
//
#include <hip/hip_runtime.h>

#define B_ 4
#define S_ 2
#define C_ 6
#define F_ 512
#define N_ 2000
#define CH_ (F_ * N_)          // stride between channels / mask slices
#define LOAD_CONST 1e-5
#define EPS_DENOM_ 1e-6
#define NV2 (N_ / 2)           // 1000 float2 per stream

// ---------------------------------------------------------------------------
// Kernel 1: masked covariances — 3 sets per wave, 2-wave blocks share X in L1.
// Session ledger: 688MB-path variants pinned at 123-133us across all MLP/TLP/
// vector-width changes (r13-r17); the only lever that moved cov was path-byte
// reduction (1.33GB->688MB: 146->123). This round: wave=(bf,s) computes all 3
// i-sets (108 acc regs); the block's 2 waves read the SAME 12 X streams on one
// CU -> L1 dedupes -> L2 path 295-491 MB.
// Registers: 108 acc + 30 float2 data ~= 148 live under (128,2) 256 cap; the
// compiler serializes loads rather than spill when tight (r15: 100 live in 84
// granted, no spill). WRITE_SIZE = spill tripwire.
// XCD-bijective swizzle (nwg=2048, %8==0).
// ---------------------------------------------------------------------------
__global__ __launch_bounds__(128, 2) void cov_kernel(
    const float* __restrict__ Xre, const float* __restrict__ Xim,
    const float* __restrict__ masks, float* __restrict__ cov) {
  const int nwg = B_ * F_;                   // 2048, %8==0 -> bijective
  const int cpx = nwg / 8;                   // 256 per XCD
  const int Bh = blockIdx.x;
  const int bf = (Bh & 7) * cpx + (Bh >> 3); // XCD-contiguous logical id
  const int b = bf / F_;
  const int f = bf - b * F_;
  const int s = threadIdx.x >> 6;            // wave id = s (0/1)
  const int lane = threadIdx.x & 63;

  const size_t xb = (size_t)b * C_ * CH_ + (size_t)f * N_;

  const float2* xrp[6];
  const float2* xip[6];
#pragma unroll
  for (int c = 0; c < 6; ++c) {
    xrp[c] = (const float2*)(Xre + xb + (size_t)c * CH_);
    xip[c] = (const float2*)(Xim + xb + (size_t)c * CH_);
  }
  const float2* mp[3];
#pragma unroll
  for (int i = 0; i < 3; ++i)
    mp[i] = (const float2*)(masks + ((size_t)b * 6 + s * 3 + i) * CH_ +
                            (size_t)f * N_);

  float accd[3][6] = {};
  float accr[3][15] = {};
  float acci[3][15] = {};

  // 1000 float2 / 64 lanes -> 16 iterations; tail via clamp + m=0.
  for (int it = 0; it < 16; ++it) {
    const int idx = lane + it * 64;
    const int a = (idx < NV2) ? idx : (NV2 - 1);

    // ---- issue all 15 float2 loads before compute (30 data VGPRs) ----
    float2 m[3];
#pragma unroll
    for (int i = 0; i < 3; ++i) m[i] = mp[i][a];
    float2 xr[6], xi[6];
#pragma unroll
    for (int c = 0; c < 6; ++c) {
      xr[c] = xrp[c][a];
      xi[c] = xip[c][a];
    }
    if (idx >= NV2) {
#pragma unroll
      for (int i = 0; i < 3; ++i) m[i] = make_float2(0.f, 0.f);
    }

    // ---- 2 elements; products x_c*x_d shared across the 3 masks ----
#pragma unroll
    for (int e = 0; e < 2; ++e) {
      float xre[6], xie[6];
#pragma unroll
      for (int c = 0; c < 6; ++c) {
        xre[c] = e ? xr[c].y : xr[c].x;
        xie[c] = e ? xi[c].y : xi[c].x;
      }
      float mm[3];
#pragma unroll
      for (int i = 0; i < 3; ++i) mm[i] = e ? m[i].y : m[i].x;

#pragma unroll
      for (int c = 0; c < 6; ++c) {
        const float d = fmaf(xre[c], xre[c], xie[c] * xie[c]);
#pragma unroll
        for (int i = 0; i < 3; ++i) accd[i][c] = fmaf(mm[i], d, accd[i][c]);
      }
      int p = 0;
#pragma unroll
      for (int c = 0; c < 6; ++c) {
#pragma unroll
        for (int d2 = c + 1; d2 < 6; ++d2) {
          const float pr = fmaf(xre[c], xre[d2], xie[c] * xie[d2]);
          const float pi = fmaf(xie[c], xre[d2], -(xre[c] * xie[d2]));
#pragma unroll
          for (int i = 0; i < 3; ++i) {
            accr[i][p] = fmaf(mm[i], pr, accr[i][p]);
            acci[i][p] = fmaf(mm[i], pi, acci[i][p]);
          }
          ++p;
        }
      }
    }
  }

  // deterministic 64-lane butterfly reduce (3 sets)
#pragma unroll
  for (int i = 0; i < 3; ++i) {
#pragma unroll
    for (int c = 0; c < 6; ++c) {
#pragma unroll
      for (int o = 32; o > 0; o >>= 1)
        accd[i][c] += __shfl_xor(accd[i][c], o, 64);
    }
#pragma unroll
    for (int p2 = 0; p2 < 15; ++p2) {
#pragma unroll
      for (int o = 32; o > 0; o >>= 1) {
        accr[i][p2] += __shfl_xor(accr[i][p2], o, 64);
        acci[i][p2] += __shfl_xor(acci[i][p2], o, 64);
      }
    }
  }

  if (lane == 0) {
#pragma unroll
    for (int i = 0; i < 3; ++i) {
      float* o = cov + ((size_t)bf * 6 + s * 3 + i) * 36;
#pragma unroll
      for (int c = 0; c < 6; ++c) o[c] = accd[i][c];
#pragma unroll
      for (int p2 = 0; p2 < 15; ++p2) {
        o[6 + 2 * p2] = accr[i][p2];
        o[7 + 2 * p2] = acci[i][p2];
      }
    }
  }
}

// ---------------------------------------------------------------------------
// Kernel 2 helpers (fp64, fully unrolled 6x6 complex linear algebra).
// ---------------------------------------------------------------------------
__device__ __forceinline__ void load_herm(const float* __restrict__ p,
                                          double* mr, double* mi) {
#pragma unroll
  for (int c = 0; c < 6; ++c) { mr[c * 6 + c] = (double)p[c]; mi[c * 6 + c] = 0.0; }
#pragma unroll
  for (int c = 0; c < 6; ++c) {
#pragma unroll
    for (int d = c + 1; d < 6; ++d) {
      const int pidx = 6 + 2 * ((11 - c) * c / 2 + (d - c - 1));
      double re = (double)p[pidx];
      double im = (double)p[pidx + 1];
      mr[c * 6 + d] = re;  mi[c * 6 + d] = im;
      mr[d * 6 + c] = re;  mi[d * 6 + c] = -im;
    }
  }
}

// Cholesky, lower triangle in place (reads lower+diag only). Diag real.
__device__ __forceinline__ void chol6(double* mr, double* mi) {
#pragma unroll
  for (int k = 0; k < 6; ++k) {
    double d = mr[k * 6 + k];
#pragma unroll
    for (int j = 0; j < 6; ++j) {
      if (j < k) d -= mr[k * 6 + j] * mr[k * 6 + j] + mi[k * 6 + j] * mi[k * 6 + j];
    }
    d = sqrt(fmax(d, 1e-300));
    mr[k * 6 + k] = d;  mi[k * 6 + k] = 0.0;
    double inv = 1.0 / d;
#pragma unroll
    for (int r = k + 1; r < 6; ++r) {
      double xre = mr[r * 6 + k], xim = mi[r * 6 + k];
#pragma unroll
      for (int j = 0; j < 6; ++j) {
        if (j < k) {
          double ar = mr[r * 6 + j], ai = mi[r * 6 + j];
          double br = mr[k * 6 + j], bi = mi[k * 6 + j];
          xre -= ar * br + ai * bi;     // L[r][j] * conj(L[k][j])
          xim -= ai * br - ar * bi;
        }
      }
      mr[r * 6 + k] = xre * inv;  mi[r * 6 + k] = xim * inv;
    }
  }
}

// forward (L y = rhs) then backward (L^H x = y), L lower in mr/mi.
__device__ __forceinline__ void chol_solve(const double* mr, const double* mi,
                                           double* xr, double* xi) {
  double yr[6], yi[6];
#pragma unroll
  for (int r = 0; r < 6; ++r) {
    double tr = xr[r], ti = xi[r];
#pragma unroll
    for (int k = 0; k < 6; ++k) {
      if (k < r) {
        double ar = mr[r * 6 + k], ai = mi[r * 6 + k];
        tr -= ar * yr[k] - ai * yi[k];
        ti -= ar * yi[k] + ai * yr[k];
      }
    }
    double inv = 1.0 / mr[r * 6 + r];
    yr[r] = tr * inv;  yi[r] = ti * inv;
  }
#pragma unroll
  for (int r = 5; r >= 0; --r) {
    double tr = yr[r], ti = yi[r];
#pragma unroll
    for (int k = 5; k >= 0; --k) {
      if (k > r) {
        double ar = mr[k * 6 + r], ai = -mi[k * 6 + r];  // conj(L[k][r])
        tr -= ar * xr[k] - ai * xi[k];
        ti -= ar * xi[k] + ai * xr[k];
      }
    }
    double inv = 1.0 / mr[r * 6 + r];
    xr[r] = tr * inv;  xi[r] = ti * inv;
  }
}

// ---------------------------------------------------------------------------
// Kernel 2: per-(b,s,f) GEVD rtf + MVDR weights, fp64, one thread per problem.
// Jacobi at 6 sweeps (r17-verified: absmax unchanged).
// ---------------------------------------------------------------------------
__global__ __launch_bounds__(64, 1) void solve_kernel(
    const float* __restrict__ cov, float* __restrict__ wts) {
  const int t = blockIdx.x * 64 + threadIdx.x;
  if (t >= B_ * S_ * F_) return;
  const int f = t % F_;
  const int s = (t / F_) % S_;
  const int b = t / (F_ * S_);
  const float* cb = cov + (((size_t)(b * F_ + f)) * 6 + s * 3) * 36;

  // --- L = chol(noise2 + load*I)
  double Lr[36], Li[36];
  load_herm(cb + 72, Lr, Li);
#pragma unroll
  for (int k = 0; k < 6; ++k) Lr[k * 6 + k] += LOAD_CONST;
  chol6(Lr, Li);

  // --- A = target covariance
  double Ar[36], Ai[36];
  load_herm(cb, Ar, Ai);

  // --- C = herm(L^{-1} A L^{-H}), upper+diag stored (diag imag = 0)
  double Cr[36], Ci[36];
#pragma unroll
  for (int k = 0; k < 36; ++k) { Cr[k] = 0.0; Ci[k] = 0.0; }
#pragma unroll
  for (int j = 0; j < 6; ++j) {
    // y = L^{-H} e_j
    double yr[6], yi[6];
#pragma unroll
    for (int r = 5; r >= 0; --r) {
      double tr = (r == j) ? 1.0 : 0.0, ti = 0.0;
#pragma unroll
      for (int k = 5; k >= 0; --k) {
        if (k > r) {
          double ar = Lr[k * 6 + r], ai = -Li[k * 6 + r];
          tr -= ar * yr[k] - ai * yi[k];
          ti -= ar * yi[k] + ai * yr[k];
        }
      }
      double inv = 1.0 / Lr[r * 6 + r];
      yr[r] = tr * inv;  yi[r] = ti * inv;
    }
    // z = A y
    double zr[6], zi[6];
#pragma unroll
    for (int r = 0; r < 6; ++r) {
      double tr = 0, ti = 0;
#pragma unroll
      for (int k = 0; k < 6; ++k) {
        double ar = Ar[r * 6 + k], ai = Ai[r * 6 + k];
        tr += ar * yr[k] - ai * yi[k];
        ti += ar * yi[k] + ai * yr[k];
      }
      zr[r] = tr;  zi[r] = ti;
    }
    // c_j = L^{-1} z
    double cr[6], ci2[6];
#pragma unroll
    for (int r = 0; r < 6; ++r) {
      double tr = zr[r], ti = zi[r];
#pragma unroll
      for (int k = 0; k < 6; ++k) {
        if (k < r) {
          double ar = Lr[r * 6 + k], ai = Li[r * 6 + k];
          tr -= ar * cr[k] - ai * ci2[k];
          ti -= ar * ci2[k] + ai * cr[k];
        }
      }
      double inv = 1.0 / Lr[r * 6 + r];
      cr[r] = tr * inv;  ci2[r] = ti * inv;
    }
    // hermitized accumulate: C = 0.5(C0 + C0^H)
#pragma unroll
    for (int r = 0; r < 6; ++r) {
      if (r < j)       { Cr[r * 6 + j] += 0.5 * cr[r];  Ci[r * 6 + j] += 0.5 * ci2[r]; }
      else if (r == j) { Cr[r * 6 + r] += cr[r]; }
      else             { Cr[j * 6 + r] += 0.5 * cr[r];  Ci[j * 6 + r] -= 0.5 * ci2[r]; }
    }
  }

  // --- keep original C for inverse iteration
  double Gr[36], Gi[36];
#pragma unroll
  for (int k = 0; k < 36; ++k) { Gr[k] = Cr[k]; Gi[k] = Ci[k]; }

  // --- eigenvalue-only cyclic Jacobi (6 sweeps) on compact Hermitian C
#pragma unroll
  for (int sweep = 0; sweep < 6; ++sweep) {
#pragma unroll
    for (int p = 0; p < 5; ++p) {
#pragma unroll
      for (int q = p + 1; q < 6; ++q) {
        double gr = Cr[p * 6 + q], gi = Ci[p * 6 + q];
        double g2 = gr * gr + gi * gi;
        if (g2 > 1e-26) {
          double g = sqrt(g2);
          double wr = gr / g, wi = -gi / g;          // w = e^{-i phi}
          double alpha = Cr[p * 6 + p], beta = Cr[q * 6 + q];
          double tau = (beta - alpha) / (2.0 * g);
          double tt = (tau >= 0.0 ? 1.0 : -1.0) / (fabs(tau) + sqrt(1.0 + tau * tau));
          double cc = 1.0 / sqrt(1.0 + tt * tt);
          double ss = tt * cc;
#pragma unroll
          for (int r = 0; r < 6; ++r) {
            if (r == p || r == q) continue;
            double rpr = (r < p) ? Cr[r * 6 + p] : Cr[p * 6 + r];
            double rpi = (r < p) ? Ci[r * 6 + p] : -Ci[p * 6 + r];
            double rqr = (r < q) ? Cr[r * 6 + q] : Cr[q * 6 + r];
            double rqi = (r < q) ? Ci[r * 6 + q] : -Ci[q * 6 + r];
            double wqr = wr * rqr - wi * rqi;        // w * a_rq
            double wqi = wr * rqi + wi * rqr;
            double nrpr = cc * rpr - ss * wqr;
            double nrpi = cc * rpi - ss * wqi;
            double nrqr = ss * rpr + cc * wqr;
            double nrqi = ss * rpi + cc * wqi;
            if (r < p) { Cr[r * 6 + p] = nrpr;  Ci[r * 6 + p] = nrpi; }
            else       { Cr[p * 6 + r] = nrpr;  Ci[p * 6 + r] = -nrpi; }
            if (r < q) { Cr[r * 6 + q] = nrqr;  Ci[r * 6 + q] = nrqi; }
            else       { Cr[q * 6 + r] = nrqr;  Ci[q * 6 + r] = -nrqi; }
          }
          Cr[p * 6 + p] = alpha - tt * g;
          Cr[q * 6 + q] = beta + tt * g;
          Cr[p * 6 + q] = 0.0;  Ci[p * 6 + q] = 0.0;
        }
      }
    }
  }

  double lmax = Cr[0];
  lmax = fmax(lmax, Cr[7]);  lmax = fmax(lmax, Cr[14]);
  lmax = fmax(lmax, Cr[21]); lmax = fmax(lmax, Cr[28]);
  lmax = fmax(lmax, Cr[35]);

  // --- M = shift*I - C_orig (PD), chol, 2x inverse iteration
  double Mr[36], Mi[36];
  double shift = lmax + fmax(1e-8 * fabs(lmax), 1e-30);
#pragma unroll
  for (int r = 0; r < 6; ++r) {
#pragma unroll
    for (int c = 0; c < 6; ++c) {
      double gre, gim;
      if (r == c)     { gre = Gr[r * 6 + c]; gim = 0.0; }
      else if (r < c) { gre = Gr[r * 6 + c]; gim = Gi[r * 6 + c]; }
      else            { gre = Gr[c * 6 + r]; gim = -Gi[c * 6 + r]; }
      Mr[r * 6 + c] = (r == c) ? (shift - gre) : -gre;
      Mi[r * 6 + c] = -gim;
    }
  }
  chol6(Mr, Mi);

  double ur[6] = {1.0, 0.8, -0.6, 1.1, -0.3, 0.5};
  double ui[6] = {0.2, -0.9, 0.7, 0.1, 1.0, -0.4};
#pragma unroll
  for (int it = 0; it < 2; ++it) {
    chol_solve(Mr, Mi, ur, ui);
    double nn = 0;
#pragma unroll
    for (int r = 0; r < 6; ++r) nn += ur[r] * ur[r] + ui[r] * ui[r];
    double innv = 1.0 / sqrt(fmax(nn, 1e-300));
#pragma unroll
    for (int r = 0; r < 6; ++r) { ur[r] *= innv; ui[r] *= innv; }
  }

  // --- v = L^{-H} u
  double vr[6], vi[6];
#pragma unroll
  for (int r = 5; r >= 0; --r) {
    double tr = ur[r], ti = ui[r];
#pragma unroll
    for (int k = 5; k >= 0; --k) {
      if (k > r) {
        double ar = Lr[k * 6 + r], ai = -Li[k * 6 + r];
        tr -= ar * vr[k] - ai * vi[k];
        ti -= ar * vi[k] + ai * vr[k];
      }
    }
    double inv = 1.0 / Lr[r * 6 + r];
    vr[r] = tr * inv;  vi[r] = ti * inv;
  }

  // --- rtf = v / v[0]
  double id2 = 1.0 / (vr[0] * vr[0] + vi[0] * vi[0]);
  double rtr[6], rti[6];
#pragma unroll
  for (int r = 0; r < 6; ++r) {
    rtr[r] = (vr[r] * vr[0] + vi[r] * vi[0]) * id2;
    rti[r] = (vi[r] * vr[0] - vr[r] * vi[0]) * id2;
  }

  // --- a = (noise1 + load*I)^{-1} rtf ; w = a / max(Re(rtf^H a), eps)
  load_herm(cb + 36, Mr, Mi);
#pragma unroll
  for (int k = 0; k < 6; ++k) Mr[k * 6 + k] += LOAD_CONST;
  chol6(Mr, Mi);
  double ar2[6], ai2[6];
#pragma unroll
  for (int r = 0; r < 6; ++r) { ar2[r] = rtr[r]; ai2[r] = rti[r]; }
  chol_solve(Mr, Mi, ar2, ai2);

  double denom = 0;
#pragma unroll
  for (int r = 0; r < 6; ++r) denom += rtr[r] * ar2[r] + rti[r] * ai2[r];
  denom = fmax(denom, EPS_DENOM_);
  double idn = 1.0 / denom;

  // store conj(w) in fp32: layout [b][s][f][c][re,im]
  float* wp = wts + (size_t)t * 12;
#pragma unroll
  for (int c = 0; c < 6; ++c) {
    wp[2 * c]     = (float)(ar2[c] * idn);
    wp[2 * c + 1] = (float)(-ai2[c] * idn);
  }
}

// ---------------------------------------------------------------------------
// Kernel 3: Y[b,s,f,n] = sum_c X[b,c,f,n] * wconj[b,s,f,c]; out (B,S,F,N,2)
// float4 over n, plain float4 components (no unions).
// ---------------------------------------------------------------------------
__global__ __launch_bounds__(256) void bf_kernel(
    const float* __restrict__ Xre, const float* __restrict__ Xim,
    const float* __restrict__ wts, float* __restrict__ out) {
  const int blk = blockIdx.x;
  const int b = blk / F_;
  const int f = blk - b * F_;
  const size_t xb = (size_t)b * C_ * CH_ + (size_t)f * N_;

  float wr[2][6], wi[2][6];
#pragma unroll
  for (int s = 0; s < 2; ++s) {
    const float* wp = wts + (((size_t)(b * S_ + s)) * F_ + f) * 12;
#pragma unroll
    for (int c = 0; c < 6; ++c) { wr[s][c] = wp[2 * c]; wi[s][c] = wp[2 * c + 1]; }
  }
  float4* o0 = (float4*)(out + ((size_t)(b * S_ + 0) * F_ + f) * N_ * 2);
  float4* o1 = (float4*)(out + ((size_t)(b * S_ + 1) * F_ + f) * N_ * 2);

  const int NV = N_ / 4;  // 500
  for (int n4 = threadIdx.x; n4 < NV; n4 += 256) {
    float4 xr[6], xi[6];
#pragma unroll
    for (int c = 0; c < 6; ++c) {
      xr[c] = ((const float4*)(Xre + xb + (size_t)c * CH_))[n4];
      xi[c] = ((const float4*)(Xim + xb + (size_t)c * CH_))[n4];
    }
#pragma unroll
    for (int s = 0; s < 2; ++s) {
      float yrx = 0.f, yix = 0.f, yry = 0.f, yiy = 0.f;
      float yrz = 0.f, yiz = 0.f, yrw = 0.f, yiw = 0.f;
#pragma unroll
      for (int c = 0; c < 6; ++c) {
        const float WR = wr[s][c], WI = wi[s][c];
        yrx = fmaf(xr[c].x, WR, fmaf(-xi[c].x, WI, yrx));
        yix = fmaf(xr[c].x, WI, fmaf(xi[c].x, WR, yix));
        yry = fmaf(xr[c].y, WR, fmaf(-xi[c].y, WI, yry));
        yiy = fmaf(xr[c].y, WI, fmaf(xi[c].y, WR, yiy));
        yrz = fmaf(xr[c].z, WR, fmaf(-xi[c].z, WI, yrz));
        yiz = fmaf(xr[c].z, WI, fmaf(xi[c].z, WR, yiz));
        yrw = fmaf(xr[c].w, WR, fmaf(-xi[c].w, WI, yrw));
        yiw = fmaf(xr[c].w, WI, fmaf(xi[c].w, WR, yiw));
      }
      float4* op = s ? o1 : o0;
      op[2 * n4]     = make_float4(yrx, yix, yry, yiy);
      op[2 * n4 + 1] = make_float4(yrz, yiz, yrw, yiw);
    }
  }
}

// ---------------------------------------------------------------------------
extern "C" void kernel_launch(void* const* d_in, const int* in_sizes, int n_in,
                              void* d_out, int out_size, void* d_ws, size_t ws_size,
                              hipStream_t stream) {
  const float* Xre   = (const float*)d_in[0];
  const float* Xim   = (const float*)d_in[1];
  const float* masks = (const float*)d_in[2];
  float* out = (float*)d_out;

  float* cov = (float*)d_ws;                              // 2048*6*36 floats
  float* wts = cov + (size_t)B_ * F_ * 6 * 36;            // 4096*12 floats

  cov_kernel<<<B_ * F_, 128, 0, stream>>>(Xre, Xim, masks, cov);
  solve_kernel<<<(B_ * S_ * F_ + 63) / 64, 64, 0, stream>>>(cov, wts);
  bf_kernel<<<B_ * F_, 256, 0, stream>>>(Xre, Xim, wts, out);
}

// Round 19
// 187.070 us; speedup vs baseline: 1.0542x; 1.0542x over previous
//
#include <hip/hip_runtime.h>

#define B_ 4
#define S_ 2
#define C_ 6
#define F_ 512
#define N_ 2000
#define CH_ (F_ * N_)          // stride between channels / mask slices
#define LOAD_CONST 1e-5
#define EPS_DENOM_ 1e-6
#define NV4 (N_ / 4)           // 500 float4 per stream

// ---------------------------------------------------------------------------
// Kernel 1: masked covariances — SESSION-BEST structure (r17, 123us):
// 6144 one-wave blocks (bf,i), each wave computes BOTH s-sets (72 acc regs,
// 688 MB L2->CU path bytes), 14 float4 streams issued before compute,
// __launch_bounds__(64,2) -> 112 VGPR granted, zero spill, XCD-bijective
// swizzle (FETCH 150 MB). r18's 3-sets variant spilled (148 live > 124
// granted, WRITE 86 MB) - reverted.
// ---------------------------------------------------------------------------
__global__ __launch_bounds__(64, 2) void cov_kernel(
    const float* __restrict__ Xre, const float* __restrict__ Xim,
    const float* __restrict__ masks, float* __restrict__ cov) {
  const int nwg = B_ * F_ * 3;               // 6144, %8==0 -> bijective
  const int cpx = nwg / 8;                   // 768 per XCD
  const int Bh = blockIdx.x;
  const int l = (Bh & 7) * cpx + (Bh >> 3);  // XCD-contiguous logical id
  const int bf = l / 3;
  const int i = l - bf * 3;
  const int b = bf / F_;
  const int f = bf - b * F_;
  const int lane = threadIdx.x;              // 0..63

  const size_t xb = (size_t)b * C_ * CH_ + (size_t)f * N_;

  const float4* xrp[6];
  const float4* xip[6];
#pragma unroll
  for (int c = 0; c < 6; ++c) {
    xrp[c] = (const float4*)(Xre + xb + (size_t)c * CH_);
    xip[c] = (const float4*)(Xim + xb + (size_t)c * CH_);
  }
  const float4* mp0 =
      (const float4*)(masks + ((size_t)b * 6 + i) * CH_ + (size_t)f * N_);
  const float4* mp1 =
      (const float4*)(masks + ((size_t)b * 6 + 3 + i) * CH_ + (size_t)f * N_);

  float acc0d[6] = {}, acc0r[15] = {}, acc0i[15] = {};
  float acc1d[6] = {}, acc1r[15] = {}, acc1i[15] = {};

  // 500 float4 / 64 lanes -> 8 iterations; tail via clamp + m=0.
  for (int it = 0; it < 8; ++it) {
    const int idx = lane + it * 64;
    const int a = (idx < NV4) ? idx : (NV4 - 1);

    // ---- issue all 14 float4 loads before compute (56 data VGPRs) ----
    float4 m0 = mp0[a];
    float4 m1 = mp1[a];
    float4 xr[6], xi[6];
#pragma unroll
    for (int c = 0; c < 6; ++c) {
      xr[c] = xrp[c][a];
      xi[c] = xip[c][a];
    }
    if (idx >= NV4) {
      m0 = make_float4(0.f, 0.f, 0.f, 0.f);
      m1 = make_float4(0.f, 0.f, 0.f, 0.f);
    }

    // ---- 4 elements; products x_c*x_d shared across both masks ----
#pragma unroll
    for (int e = 0; e < 4; ++e) {
      float xre[6], xie[6];
#pragma unroll
      for (int c = 0; c < 6; ++c) {
        xre[c] = (e == 0) ? xr[c].x : (e == 1) ? xr[c].y : (e == 2) ? xr[c].z : xr[c].w;
        xie[c] = (e == 0) ? xi[c].x : (e == 1) ? xi[c].y : (e == 2) ? xi[c].z : xi[c].w;
      }
      const float mm0 = (e == 0) ? m0.x : (e == 1) ? m0.y : (e == 2) ? m0.z : m0.w;
      const float mm1 = (e == 0) ? m1.x : (e == 1) ? m1.y : (e == 2) ? m1.z : m1.w;

#pragma unroll
      for (int c = 0; c < 6; ++c) {
        const float d = fmaf(xre[c], xre[c], xie[c] * xie[c]);
        acc0d[c] = fmaf(mm0, d, acc0d[c]);
        acc1d[c] = fmaf(mm1, d, acc1d[c]);
      }
      int p = 0;
#pragma unroll
      for (int c = 0; c < 6; ++c) {
#pragma unroll
        for (int d2 = c + 1; d2 < 6; ++d2) {
          const float pr = fmaf(xre[c], xre[d2], xie[c] * xie[d2]);
          const float pi = fmaf(xie[c], xre[d2], -(xre[c] * xie[d2]));
          acc0r[p] = fmaf(mm0, pr, acc0r[p]);
          acc0i[p] = fmaf(mm0, pi, acc0i[p]);
          acc1r[p] = fmaf(mm1, pr, acc1r[p]);
          acc1i[p] = fmaf(mm1, pi, acc1i[p]);
          ++p;
        }
      }
    }
  }

  // deterministic 64-lane butterfly reduce (both sets)
#pragma unroll
  for (int c = 0; c < 6; ++c) {
#pragma unroll
    for (int o = 32; o > 0; o >>= 1) {
      acc0d[c] += __shfl_xor(acc0d[c], o, 64);
      acc1d[c] += __shfl_xor(acc1d[c], o, 64);
    }
  }
#pragma unroll
  for (int p2 = 0; p2 < 15; ++p2) {
#pragma unroll
    for (int o = 32; o > 0; o >>= 1) {
      acc0r[p2] += __shfl_xor(acc0r[p2], o, 64);
      acc0i[p2] += __shfl_xor(acc0i[p2], o, 64);
      acc1r[p2] += __shfl_xor(acc1r[p2], o, 64);
      acc1i[p2] += __shfl_xor(acc1i[p2], o, 64);
    }
  }

  if (lane == 0) {
    float* o0 = cov + ((size_t)bf * 6 + i) * 36;       // set j = i   (s=0)
    float* o1 = cov + ((size_t)bf * 6 + 3 + i) * 36;   // set j = 3+i (s=1)
#pragma unroll
    for (int c = 0; c < 6; ++c) { o0[c] = acc0d[c]; o1[c] = acc1d[c]; }
#pragma unroll
    for (int p2 = 0; p2 < 15; ++p2) {
      o0[6 + 2 * p2] = acc0r[p2];  o0[7 + 2 * p2] = acc0i[p2];
      o1[6 + 2 * p2] = acc1r[p2];  o1[7 + 2 * p2] = acc1i[p2];
    }
  }
}

// ---------------------------------------------------------------------------
// Kernel 2 helpers (fp64, fully unrolled 6x6 complex linear algebra).
// ---------------------------------------------------------------------------
__device__ __forceinline__ void load_herm(const float* __restrict__ p,
                                          double* mr, double* mi) {
#pragma unroll
  for (int c = 0; c < 6; ++c) { mr[c * 6 + c] = (double)p[c]; mi[c * 6 + c] = 0.0; }
#pragma unroll
  for (int c = 0; c < 6; ++c) {
#pragma unroll
    for (int d = c + 1; d < 6; ++d) {
      const int pidx = 6 + 2 * ((11 - c) * c / 2 + (d - c - 1));
      double re = (double)p[pidx];
      double im = (double)p[pidx + 1];
      mr[c * 6 + d] = re;  mi[c * 6 + d] = im;
      mr[d * 6 + c] = re;  mi[d * 6 + c] = -im;
    }
  }
}

// Cholesky, lower triangle in place (reads lower+diag only). Diag real.
__device__ __forceinline__ void chol6(double* mr, double* mi) {
#pragma unroll
  for (int k = 0; k < 6; ++k) {
    double d = mr[k * 6 + k];
#pragma unroll
    for (int j = 0; j < 6; ++j) {
      if (j < k) d -= mr[k * 6 + j] * mr[k * 6 + j] + mi[k * 6 + j] * mi[k * 6 + j];
    }
    d = sqrt(fmax(d, 1e-300));
    mr[k * 6 + k] = d;  mi[k * 6 + k] = 0.0;
    double inv = 1.0 / d;
#pragma unroll
    for (int r = k + 1; r < 6; ++r) {
      double xre = mr[r * 6 + k], xim = mi[r * 6 + k];
#pragma unroll
      for (int j = 0; j < 6; ++j) {
        if (j < k) {
          double ar = mr[r * 6 + j], ai = mi[r * 6 + j];
          double br = mr[k * 6 + j], bi = mi[k * 6 + j];
          xre -= ar * br + ai * bi;     // L[r][j] * conj(L[k][j])
          xim -= ai * br - ar * bi;
        }
      }
      mr[r * 6 + k] = xre * inv;  mi[r * 6 + k] = xim * inv;
    }
  }
}

// forward (L y = rhs) then backward (L^H x = y), L lower in mr/mi.
__device__ __forceinline__ void chol_solve(const double* mr, const double* mi,
                                           double* xr, double* xi) {
  double yr[6], yi[6];
#pragma unroll
  for (int r = 0; r < 6; ++r) {
    double tr = xr[r], ti = xi[r];
#pragma unroll
    for (int k = 0; k < 6; ++k) {
      if (k < r) {
        double ar = mr[r * 6 + k], ai = mi[r * 6 + k];
        tr -= ar * yr[k] - ai * yi[k];
        ti -= ar * yi[k] + ai * yr[k];
      }
    }
    double inv = 1.0 / mr[r * 6 + r];
    yr[r] = tr * inv;  yi[r] = ti * inv;
  }
#pragma unroll
  for (int r = 5; r >= 0; --r) {
    double tr = yr[r], ti = yi[r];
#pragma unroll
    for (int k = 5; k >= 0; --k) {
      if (k > r) {
        double ar = mr[k * 6 + r], ai = -mi[k * 6 + r];  // conj(L[k][r])
        tr -= ar * xr[k] - ai * xi[k];
        ti -= ar * xi[k] + ai * xr[k];
      }
    }
    double inv = 1.0 / mr[r * 6 + r];
    xr[r] = tr * inv;  xi[r] = ti * inv;
  }
}

// ---------------------------------------------------------------------------
// Kernel 2: per-(b,s,f) GEVD rtf + MVDR weights, fp64, one thread per problem.
// Jacobi at 6 sweeps (r17-verified: absmax unchanged).
// ---------------------------------------------------------------------------
__global__ __launch_bounds__(64, 1) void solve_kernel(
    const float* __restrict__ cov, float* __restrict__ wts) {
  const int t = blockIdx.x * 64 + threadIdx.x;
  if (t >= B_ * S_ * F_) return;
  const int f = t % F_;
  const int s = (t / F_) % S_;
  const int b = t / (F_ * S_);
  const float* cb = cov + (((size_t)(b * F_ + f)) * 6 + s * 3) * 36;

  // --- L = chol(noise2 + load*I)
  double Lr[36], Li[36];
  load_herm(cb + 72, Lr, Li);
#pragma unroll
  for (int k = 0; k < 6; ++k) Lr[k * 6 + k] += LOAD_CONST;
  chol6(Lr, Li);

  // --- A = target covariance
  double Ar[36], Ai[36];
  load_herm(cb, Ar, Ai);

  // --- C = herm(L^{-1} A L^{-H}), upper+diag stored (diag imag = 0)
  double Cr[36], Ci[36];
#pragma unroll
  for (int k = 0; k < 36; ++k) { Cr[k] = 0.0; Ci[k] = 0.0; }
#pragma unroll
  for (int j = 0; j < 6; ++j) {
    // y = L^{-H} e_j
    double yr[6], yi[6];
#pragma unroll
    for (int r = 5; r >= 0; --r) {
      double tr = (r == j) ? 1.0 : 0.0, ti = 0.0;
#pragma unroll
      for (int k = 5; k >= 0; --k) {
        if (k > r) {
          double ar = Lr[k * 6 + r], ai = -Li[k * 6 + r];
          tr -= ar * yr[k] - ai * yi[k];
          ti -= ar * yi[k] + ai * yr[k];
        }
      }
      double inv = 1.0 / Lr[r * 6 + r];
      yr[r] = tr * inv;  yi[r] = ti * inv;
    }
    // z = A y
    double zr[6], zi[6];
#pragma unroll
    for (int r = 0; r < 6; ++r) {
      double tr = 0, ti = 0;
#pragma unroll
      for (int k = 0; k < 6; ++k) {
        double ar = Ar[r * 6 + k], ai = Ai[r * 6 + k];
        tr += ar * yr[k] - ai * yi[k];
        ti += ar * yi[k] + ai * yr[k];
      }
      zr[r] = tr;  zi[r] = ti;
    }
    // c_j = L^{-1} z
    double cr[6], ci2[6];
#pragma unroll
    for (int r = 0; r < 6; ++r) {
      double tr = zr[r], ti = zi[r];
#pragma unroll
      for (int k = 0; k < 6; ++k) {
        if (k < r) {
          double ar = Lr[r * 6 + k], ai = Li[r * 6 + k];
          tr -= ar * cr[k] - ai * ci2[k];
          ti -= ar * ci2[k] + ai * cr[k];
        }
      }
      double inv = 1.0 / Lr[r * 6 + r];
      cr[r] = tr * inv;  ci2[r] = ti * inv;
    }
    // hermitized accumulate: C = 0.5(C0 + C0^H)
#pragma unroll
    for (int r = 0; r < 6; ++r) {
      if (r < j)       { Cr[r * 6 + j] += 0.5 * cr[r];  Ci[r * 6 + j] += 0.5 * ci2[r]; }
      else if (r == j) { Cr[r * 6 + r] += cr[r]; }
      else             { Cr[j * 6 + r] += 0.5 * cr[r];  Ci[j * 6 + r] -= 0.5 * ci2[r]; }
    }
  }

  // --- keep original C for inverse iteration
  double Gr[36], Gi[36];
#pragma unroll
  for (int k = 0; k < 36; ++k) { Gr[k] = Cr[k]; Gi[k] = Ci[k]; }

  // --- eigenvalue-only cyclic Jacobi (6 sweeps) on compact Hermitian C
#pragma unroll
  for (int sweep = 0; sweep < 6; ++sweep) {
#pragma unroll
    for (int p = 0; p < 5; ++p) {
#pragma unroll
      for (int q = p + 1; q < 6; ++q) {
        double gr = Cr[p * 6 + q], gi = Ci[p * 6 + q];
        double g2 = gr * gr + gi * gi;
        if (g2 > 1e-26) {
          double g = sqrt(g2);
          double wr = gr / g, wi = -gi / g;          // w = e^{-i phi}
          double alpha = Cr[p * 6 + p], beta = Cr[q * 6 + q];
          double tau = (beta - alpha) / (2.0 * g);
          double tt = (tau >= 0.0 ? 1.0 : -1.0) / (fabs(tau) + sqrt(1.0 + tau * tau));
          double cc = 1.0 / sqrt(1.0 + tt * tt);
          double ss = tt * cc;
#pragma unroll
          for (int r = 0; r < 6; ++r) {
            if (r == p || r == q) continue;
            double rpr = (r < p) ? Cr[r * 6 + p] : Cr[p * 6 + r];
            double rpi = (r < p) ? Ci[r * 6 + p] : -Ci[p * 6 + r];
            double rqr = (r < q) ? Cr[r * 6 + q] : Cr[q * 6 + r];
            double rqi = (r < q) ? Ci[r * 6 + q] : -Ci[q * 6 + r];
            double wqr = wr * rqr - wi * rqi;        // w * a_rq
            double wqi = wr * rqi + wi * rqr;
            double nrpr = cc * rpr - ss * wqr;
            double nrpi = cc * rpi - ss * wqi;
            double nrqr = ss * rpr + cc * wqr;
            double nrqi = ss * rpi + cc * wqi;
            if (r < p) { Cr[r * 6 + p] = nrpr;  Ci[r * 6 + p] = nrpi; }
            else       { Cr[p * 6 + r] = nrpr;  Ci[p * 6 + r] = -nrpi; }
            if (r < q) { Cr[r * 6 + q] = nrqr;  Ci[r * 6 + q] = nrqi; }
            else       { Cr[q * 6 + r] = nrqr;  Ci[q * 6 + r] = -nrqi; }
          }
          Cr[p * 6 + p] = alpha - tt * g;
          Cr[q * 6 + q] = beta + tt * g;
          Cr[p * 6 + q] = 0.0;  Ci[p * 6 + q] = 0.0;
        }
      }
    }
  }

  double lmax = Cr[0];
  lmax = fmax(lmax, Cr[7]);  lmax = fmax(lmax, Cr[14]);
  lmax = fmax(lmax, Cr[21]); lmax = fmax(lmax, Cr[28]);
  lmax = fmax(lmax, Cr[35]);

  // --- M = shift*I - C_orig (PD), chol, 2x inverse iteration
  double Mr[36], Mi[36];
  double shift = lmax + fmax(1e-8 * fabs(lmax), 1e-30);
#pragma unroll
  for (int r = 0; r < 6; ++r) {
#pragma unroll
    for (int c = 0; c < 6; ++c) {
      double gre, gim;
      if (r == c)     { gre = Gr[r * 6 + c]; gim = 0.0; }
      else if (r < c) { gre = Gr[r * 6 + c]; gim = Gi[r * 6 + c]; }
      else            { gre = Gr[c * 6 + r]; gim = -Gi[c * 6 + r]; }
      Mr[r * 6 + c] = (r == c) ? (shift - gre) : -gre;
      Mi[r * 6 + c] = -gim;
    }
  }
  chol6(Mr, Mi);

  double ur[6] = {1.0, 0.8, -0.6, 1.1, -0.3, 0.5};
  double ui[6] = {0.2, -0.9, 0.7, 0.1, 1.0, -0.4};
#pragma unroll
  for (int it = 0; it < 2; ++it) {
    chol_solve(Mr, Mi, ur, ui);
    double nn = 0;
#pragma unroll
    for (int r = 0; r < 6; ++r) nn += ur[r] * ur[r] + ui[r] * ui[r];
    double innv = 1.0 / sqrt(fmax(nn, 1e-300));
#pragma unroll
    for (int r = 0; r < 6; ++r) { ur[r] *= innv; ui[r] *= innv; }
  }

  // --- v = L^{-H} u
  double vr[6], vi[6];
#pragma unroll
  for (int r = 5; r >= 0; --r) {
    double tr = ur[r], ti = ui[r];
#pragma unroll
    for (int k = 5; k >= 0; --k) {
      if (k > r) {
        double ar = Lr[k * 6 + r], ai = -Li[k * 6 + r];
        tr -= ar * vr[k] - ai * vi[k];
        ti -= ar * vi[k] + ai * vr[k];
      }
    }
    double inv = 1.0 / Lr[r * 6 + r];
    vr[r] = tr * inv;  vi[r] = ti * inv;
  }

  // --- rtf = v / v[0]
  double id2 = 1.0 / (vr[0] * vr[0] + vi[0] * vi[0]);
  double rtr[6], rti[6];
#pragma unroll
  for (int r = 0; r < 6; ++r) {
    rtr[r] = (vr[r] * vr[0] + vi[r] * vi[0]) * id2;
    rti[r] = (vi[r] * vr[0] - vr[r] * vi[0]) * id2;
  }

  // --- a = (noise1 + load*I)^{-1} rtf ; w = a / max(Re(rtf^H a), eps)
  load_herm(cb + 36, Mr, Mi);
#pragma unroll
  for (int k = 0; k < 6; ++k) Mr[k * 6 + k] += LOAD_CONST;
  chol6(Mr, Mi);
  double ar2[6], ai2[6];
#pragma unroll
  for (int r = 0; r < 6; ++r) { ar2[r] = rtr[r]; ai2[r] = rti[r]; }
  chol_solve(Mr, Mi, ar2, ai2);

  double denom = 0;
#pragma unroll
  for (int r = 0; r < 6; ++r) denom += rtr[r] * ar2[r] + rti[r] * ai2[r];
  denom = fmax(denom, EPS_DENOM_);
  double idn = 1.0 / denom;

  // store conj(w) in fp32: layout [b][s][f][c][re,im]
  float* wp = wts + (size_t)t * 12;
#pragma unroll
  for (int c = 0; c < 6; ++c) {
    wp[2 * c]     = (float)(ar2[c] * idn);
    wp[2 * c + 1] = (float)(-ai2[c] * idn);
  }
}

// ---------------------------------------------------------------------------
// Kernel 3: Y[b,s,f,n] = sum_c X[b,c,f,n] * wconj[b,s,f,c]; out (B,S,F,N,2)
// float4 over n, plain float4 components (no unions).
// ---------------------------------------------------------------------------
__global__ __launch_bounds__(256) void bf_kernel(
    const float* __restrict__ Xre, const float* __restrict__ Xim,
    const float* __restrict__ wts, float* __restrict__ out) {
  const int blk = blockIdx.x;
  const int b = blk / F_;
  const int f = blk - b * F_;
  const size_t xb = (size_t)b * C_ * CH_ + (size_t)f * N_;

  float wr[2][6], wi[2][6];
#pragma unroll
  for (int s = 0; s < 2; ++s) {
    const float* wp = wts + (((size_t)(b * S_ + s)) * F_ + f) * 12;
#pragma unroll
    for (int c = 0; c < 6; ++c) { wr[s][c] = wp[2 * c]; wi[s][c] = wp[2 * c + 1]; }
  }
  float4* o0 = (float4*)(out + ((size_t)(b * S_ + 0) * F_ + f) * N_ * 2);
  float4* o1 = (float4*)(out + ((size_t)(b * S_ + 1) * F_ + f) * N_ * 2);

  const int NV = N_ / 4;  // 500
  for (int n4 = threadIdx.x; n4 < NV; n4 += 256) {
    float4 xr[6], xi[6];
#pragma unroll
    for (int c = 0; c < 6; ++c) {
      xr[c] = ((const float4*)(Xre + xb + (size_t)c * CH_))[n4];
      xi[c] = ((const float4*)(Xim + xb + (size_t)c * CH_))[n4];
    }
#pragma unroll
    for (int s = 0; s < 2; ++s) {
      float yrx = 0.f, yix = 0.f, yry = 0.f, yiy = 0.f;
      float yrz = 0.f, yiz = 0.f, yrw = 0.f, yiw = 0.f;
#pragma unroll
      for (int c = 0; c < 6; ++c) {
        const float WR = wr[s][c], WI = wi[s][c];
        yrx = fmaf(xr[c].x, WR, fmaf(-xi[c].x, WI, yrx));
        yix = fmaf(xr[c].x, WI, fmaf(xi[c].x, WR, yix));
        yry = fmaf(xr[c].y, WR, fmaf(-xi[c].y, WI, yry));
        yiy = fmaf(xr[c].y, WI, fmaf(xi[c].y, WR, yiy));
        yrz = fmaf(xr[c].z, WR, fmaf(-xi[c].z, WI, yrz));
        yiz = fmaf(xr[c].z, WI, fmaf(xi[c].z, WR, yiz));
        yrw = fmaf(xr[c].w, WR, fmaf(-xi[c].w, WI, yrw));
        yiw = fmaf(xr[c].w, WI, fmaf(xi[c].w, WR, yiw));
      }
      float4* op = s ? o1 : o0;
      op[2 * n4]     = make_float4(yrx, yix, yry, yiy);
      op[2 * n4 + 1] = make_float4(yrz, yiz, yrw, yiw);
    }
  }
}

// ---------------------------------------------------------------------------
extern "C" void kernel_launch(void* const* d_in, const int* in_sizes, int n_in,
                              void* d_out, int out_size, void* d_ws, size_t ws_size,
                              hipStream_t stream) {
  const float* Xre   = (const float*)d_in[0];
  const float* Xim   = (const float*)d_in[1];
  const float* masks = (const float*)d_in[2];
  float* out = (float*)d_out;

  float* cov = (float*)d_ws;                              // 2048*6*36 floats
  float* wts = cov + (size_t)B_ * F_ * 6 * 36;            // 4096*12 floats

  cov_kernel<<<B_ * F_ * 3, 64, 0, stream>>>(Xre, Xim, masks, cov);
  solve_kernel<<<(B_ * S_ * F_ + 63) / 64, 64, 0, stream>>>(cov, wts);
  bf_kernel<<<B_ * F_, 256, 0, stream>>>(Xre, Xim, wts, out);
}